// Round 7
// baseline (907.859 us; speedup 1.0000x reference)
//
#include <hip/hip_runtime.h>
#include <hip/hip_bf16.h>
#include <math.h>

#define GN 50000
#define GIN 256
#define GF 64
#define GH 4
#define GM 3
#define GE 800000
#define GOUT 16
#define HF 256          // H*F
#define MN (GM*GN)      // 150000

__device__ inline float lkexp(float x) {         // exp(leaky_relu(x))
    x = x > 0.f ? x : 0.2f * x;
    return __expf(x);                             // max-free: |logit| <~ 6, safe in f32
}

// ------ GEMM: feat[m] = h @ W_fc[m] (f32 64x64 tile) + fused el/er -------
__global__ __launch_bounds__(256) void k_gemm(const float* __restrict__ A,
                                              const float* __restrict__ W,
                                              const float* __restrict__ al,
                                              const float* __restrict__ ar,
                                              float* __restrict__ C,
                                              float* __restrict__ el,
                                              float* __restrict__ er) {
    int m = blockIdx.z;
    int rowBase = blockIdx.x * 64;
    int hh = blockIdx.y;            // head index == 64-col block
    int colBase = hh * 64;
    const float* B = W + (size_t)m * GIN * HF;
    float* Cm = C + (size_t)m * GN * HF;

    __shared__ float As[64][36];
    __shared__ float Bs[32][68];

    int tid = threadIdx.x;
    int tx = tid & 15, ty = tid >> 4;
    float acc[4][4] = {};

    for (int k0 = 0; k0 < GIN; k0 += 32) {
        #pragma unroll
        for (int l = 0; l < 2; l++) {       // A tile 64x32
            int idx = tid + l * 256;
            int r = idx >> 3, c4 = idx & 7;
            int row = rowBase + r;
            float4 v = make_float4(0.f, 0.f, 0.f, 0.f);
            if (row < GN) v = *(const float4*)&A[(size_t)row * GIN + k0 + c4 * 4];
            *(float4*)&As[r][c4 * 4] = v;
        }
        #pragma unroll
        for (int l = 0; l < 2; l++) {       // B tile 32x64
            int idx = tid + l * 256;
            int r = idx >> 4, c4 = idx & 15;
            float4 v = *(const float4*)&B[(size_t)(k0 + r) * HF + colBase + c4 * 4];
            *(float4*)&Bs[r][c4 * 4] = v;
        }
        __syncthreads();
        #pragma unroll
        for (int kk = 0; kk < 32; kk++) {
            float4 b4 = *(float4*)&Bs[kk][tx * 4];
            float a0 = As[ty * 4 + 0][kk];
            float a1 = As[ty * 4 + 1][kk];
            float a2 = As[ty * 4 + 2][kk];
            float a3 = As[ty * 4 + 3][kk];
            acc[0][0] = fmaf(a0, b4.x, acc[0][0]); acc[0][1] = fmaf(a0, b4.y, acc[0][1]);
            acc[0][2] = fmaf(a0, b4.z, acc[0][2]); acc[0][3] = fmaf(a0, b4.w, acc[0][3]);
            acc[1][0] = fmaf(a1, b4.x, acc[1][0]); acc[1][1] = fmaf(a1, b4.y, acc[1][1]);
            acc[1][2] = fmaf(a1, b4.z, acc[1][2]); acc[1][3] = fmaf(a1, b4.w, acc[1][3]);
            acc[2][0] = fmaf(a2, b4.x, acc[2][0]); acc[2][1] = fmaf(a2, b4.y, acc[2][1]);
            acc[2][2] = fmaf(a2, b4.z, acc[2][2]); acc[2][3] = fmaf(a2, b4.w, acc[2][3]);
            acc[3][0] = fmaf(a3, b4.x, acc[3][0]); acc[3][1] = fmaf(a3, b4.y, acc[3][1]);
            acc[3][2] = fmaf(a3, b4.z, acc[3][2]); acc[3][3] = fmaf(a3, b4.w, acc[3][3]);
        }
        __syncthreads();
    }
    #pragma unroll
    for (int i2 = 0; i2 < 4; i2++) {
        int row = rowBase + ty * 4 + i2;
        if (row < GN) {
            float4 v = make_float4(acc[i2][0], acc[i2][1], acc[i2][2], acc[i2][3]);
            *(float4*)&Cm[(size_t)row * HF + colBase + tx * 4] = v;
        }
    }
    // fused el/er epilogue: block owns head hh fully
    const float* alb = al + ((size_t)m * GH + hh) * GF + tx * 4;
    const float* arb = ar + ((size_t)m * GH + hh) * GF + tx * 4;
    float a0 = alb[0], a1 = alb[1], a2 = alb[2], a3 = alb[3];
    float r0 = arb[0], r1 = arb[1], r2 = arb[2], r3 = arb[3];
    float* elm = el + (size_t)m * GN * GH;
    float* erm = er + (size_t)m * GN * GH;
    #pragma unroll
    for (int i2 = 0; i2 < 4; i2++) {
        float pl = acc[i2][0] * a0 + acc[i2][1] * a1 + acc[i2][2] * a2 + acc[i2][3] * a3;
        float pr = acc[i2][0] * r0 + acc[i2][1] * r1 + acc[i2][2] * r2 + acc[i2][3] * r3;
        #pragma unroll
        for (int o = 1; o < 16; o <<= 1) {
            pl += __shfl_xor(pl, o, 16);
            pr += __shfl_xor(pr, o, 16);
        }
        int row = rowBase + ty * 4 + i2;
        if (tx == 0 && row < GN) {
            elm[(size_t)row * GH + hh] = pl;
            erm[(size_t)row * GH + hh] = pr;
        }
    }
}

// ---- bucket placement + weight precompute: 1 atomic/edge ----------------
__global__ __launch_bounds__(256) void k_place_bucket_w(const int* __restrict__ ei,
                                                        const float* __restrict__ el,
                                                        const float* __restrict__ er,
                                                        int* __restrict__ cursor,
                                                        int* __restrict__ perm,
                                                        float4* __restrict__ wbuf,
                                                        int cap) {
    int e = blockIdx.x * 256 + threadIdx.x;
    int m = blockIdx.y;
    int src = ei[((size_t)m * 2 + 0) * GE + e];
    int dst = ei[((size_t)m * 2 + 1) * GE + e];
    int nb = m * GN + dst;
    float4 l4 = *(const float4*)&el[((size_t)m * GN + src) * GH];
    float4 r4 = *(const float4*)&er[((size_t)nb) * GH];
    float4 w4 = make_float4(lkexp(l4.x + r4.x), lkexp(l4.y + r4.y),
                            lkexp(l4.z + r4.z), lkexp(l4.w + r4.w));
    int c = atomicAdd(&cursor[nb], 1);
    if (c < cap) {                                // clamp guard (P(deg>cap) ~ 0)
        perm[nb * cap + c] = src;
        wbuf[nb * cap + c] = w4;
    }
}

// ---------------- compact-CSR fallback path ------------------------------
__global__ __launch_bounds__(256) void k_deg(const int* __restrict__ ei,
                                             int* __restrict__ deg) {
    int e = blockIdx.x * 256 + threadIdx.x;
    int m = blockIdx.y;
    int dst = ei[((size_t)m * 2 + 1) * GE + e];
    atomicAdd(&deg[m * GN + dst], 1);
}

__global__ __launch_bounds__(1024) void k_scan(const int* __restrict__ deg,
                                               int* __restrict__ basearr) {
    __shared__ int s_wsum[16];
    int tid = threadIdx.x;
    int wave = tid >> 6, lane = tid & 63;
    if (tid == 0) basearr[0] = 0;
    int carry = 0;
    for (int c0 = 0; c0 < MN; c0 += 4096) {
        int idx = c0 + tid * 4;
        int v0 = (idx + 0 < MN) ? deg[idx + 0] : 0;
        int v1 = (idx + 1 < MN) ? deg[idx + 1] : 0;
        int v2 = (idx + 2 < MN) ? deg[idx + 2] : 0;
        int v3 = (idx + 3 < MN) ? deg[idx + 3] : 0;
        int s = v0 + v1 + v2 + v3;
        int sc = s;
        #pragma unroll
        for (int o = 1; o < 64; o <<= 1) {
            int u = __shfl_up(sc, o, 64);
            if (lane >= o) sc += u;
        }
        if (lane == 63) s_wsum[wave] = sc;
        __syncthreads();
        if (tid < 16) {
            int w = s_wsum[tid];
            #pragma unroll
            for (int o = 1; o < 16; o <<= 1) {
                int u = __shfl_up(w, o, 16);
                if (tid >= o) w += u;
            }
            s_wsum[tid] = w;
        }
        __syncthreads();
        int wpre = (wave == 0) ? 0 : s_wsum[wave - 1];
        int total = s_wsum[15];
        int p = carry + wpre + (sc - s);
        p += v0; if (idx + 0 < MN) basearr[idx + 1] = p;
        p += v1; if (idx + 1 < MN) basearr[idx + 2] = p;
        p += v2; if (idx + 2 < MN) basearr[idx + 3] = p;
        p += v3; if (idx + 3 < MN) basearr[idx + 4] = p;
        carry += total;
        __syncthreads();
    }
}

__global__ __launch_bounds__(256) void k_place_w(const int* __restrict__ ei,
                                                 const float* __restrict__ el,
                                                 const float* __restrict__ er,
                                                 const int* __restrict__ basearr,
                                                 int* __restrict__ cursor,
                                                 int* __restrict__ perm,
                                                 float4* __restrict__ wbuf,
                                                 int useW) {
    int e = blockIdx.x * 256 + threadIdx.x;
    int m = blockIdx.y;
    int src = ei[((size_t)m * 2 + 0) * GE + e];
    int dst = ei[((size_t)m * 2 + 1) * GE + e];
    int nb = m * GN + dst;
    int pos = basearr[nb] + atomicAdd(&cursor[nb], 1);
    perm[pos] = src;
    if (useW) {
        float4 l4 = *(const float4*)&el[((size_t)m * GN + src) * GH];
        float4 r4 = *(const float4*)&er[((size_t)nb) * GH];
        wbuf[pos] = make_float4(lkexp(l4.x + r4.x), lkexp(l4.y + r4.y),
                                lkexp(l4.z + r4.z), lkexp(l4.w + r4.w));
    }
}

// ---- aggregation: wave-per-node, zero barriers, precomputed weights -----
template<bool PRECOMP>
__global__ __launch_bounds__(256) void k_agg(const float* __restrict__ feat,
                                             const float* __restrict__ el,
                                             const float* __restrict__ er,
                                             const int* __restrict__ degArr,
                                             const int* __restrict__ basearr,
                                             const int* __restrict__ perm,
                                             const float4* __restrict__ wbuf,
                                             const float* __restrict__ Wp,
                                             const float* __restrict__ bp,
                                             float* __restrict__ out,
                                             int cap) {
    int t = threadIdx.x;
    int w = t >> 6, lane = t & 63;
    int n = blockIdx.x * 4 + w;           // GN % 4 == 0
    int m = blockIdx.y;
    int nb = m * GN + n;
    int start, deg;
    if (cap > 0) { start = nb * cap; deg = min(degArr[nb], cap); }
    else { start = basearr[nb]; deg = basearr[nb + 1] - start; }

    __shared__ float4 s_w4[4][64];        // [wave][edge] exp weights
    __shared__ int    s_off[4][64];       // [wave][edge] feat byte offset
    __shared__ float  s_z[4][256];
    __shared__ float  s_pr[4][4][16];

    const char* featb = (const char*)(feat + (size_t)m * GN * HF);
    int hl = lane >> 4;                   // head of this lane's 4 dims
    int myoff = lane * 16;

    float4 er4;
    if (!PRECOMP) er4 = *(const float4*)&er[(size_t)nb * GH];

    float4 acc  = make_float4(0.f, 0.f, 0.f, 0.f);
    float4 dsum = make_float4(0.f, 0.f, 0.f, 0.f);

    for (int done = 0; done < deg; done += 64) {
        int cnt = min(64, deg - done);
        float4 w4 = make_float4(0.f, 0.f, 0.f, 0.f);
        if (lane < cnt) {
            int src = perm[start + done + lane];
            s_off[w][lane] = src << 10;   // HF*4 bytes per row
            if (PRECOMP) {
                w4 = wbuf[start + done + lane];
            } else {
                float4 e4 = *(const float4*)&el[((size_t)m * GN + src) * GH];
                w4 = make_float4(lkexp(e4.x + er4.x), lkexp(e4.y + er4.y),
                                 lkexp(e4.z + er4.z), lkexp(e4.w + er4.w));
            }
            s_w4[w][lane] = w4;
        }
        dsum.x += w4.x; dsum.y += w4.y; dsum.z += w4.z; dsum.w += w4.w;
        // gather (intra-wave LDS RAW ordered; no barriers anywhere)
        #pragma unroll 8
        for (int i = 0; i < cnt; i++) {
            float wgt = ((const float*)&s_w4[w][i])[hl];   // bcast per 16-group
            float4 f = *(const float4*)(featb + s_off[w][i] + myoff);
            acc.x = fmaf(wgt, f.x, acc.x);
            acc.y = fmaf(wgt, f.y, acc.y);
            acc.z = fmaf(wgt, f.z, acc.z);
            acc.w = fmaf(wgt, f.w, acc.w);
        }
    }
    // single wave-reduce of the 4 denominators
    #pragma unroll
    for (int o = 32; o > 0; o >>= 1) {
        dsum.x += __shfl_xor(dsum.x, o, 64);
        dsum.y += __shfl_xor(dsum.y, o, 64);
        dsum.z += __shfl_xor(dsum.z, o, 64);
        dsum.w += __shfl_xor(dsum.w, o, 64);
    }
    float dr = (hl & 1) ? ((hl & 2) ? dsum.w : dsum.y)
                        : ((hl & 2) ? dsum.z : dsum.x);
    float inv = (deg > 0) ? 1.f / dr : 0.f;
    float4 z;
    float rx = acc.x * inv; z.x = rx > 0.f ? rx : expm1f(rx);
    float ry = acc.y * inv; z.y = ry > 0.f ? ry : expm1f(ry);
    float rz = acc.z * inv; z.z = rz > 0.f ? rz : expm1f(rz);
    float rw = acc.w * inv; z.w = rw > 0.f ? rw : expm1f(rw);
    *(float4*)&s_z[w][lane * 4] = z;

    // pred head, per-wave: lane handles (chunk ck, output o); rotated dim
    // order keeps the 4 groups on distinct LDS banks.
    int ck = lane >> 4, o = lane & 15;
    float p = 0.f;
    #pragma unroll
    for (int v = 0; v < 64; v++) {
        int dim = ck * 64 + ((v + 8 * ck) & 63);
        p = fmaf(s_z[w][dim], Wp[dim * GOUT + o], p);
    }
    s_pr[w][ck][o] = p;
    if (lane < 16) {
        float s = bp[lane] + s_pr[w][0][lane] + s_pr[w][1][lane]
                + s_pr[w][2][lane] + s_pr[w][3][lane];
        out[(size_t)n * (GM * GOUT) + m * GOUT + lane] = s;
    }
}

extern "C" void kernel_launch(void* const* d_in, const int* in_sizes, int n_in,
                              void* d_out, int out_size, void* d_ws, size_t ws_size,
                              hipStream_t stream) {
    const float* h   = (const float*)d_in[0];
    const int*   ei  = (const int*)d_in[1];
    const float* Wfc = (const float*)d_in[2];
    const float* al  = (const float*)d_in[3];
    const float* ar  = (const float*)d_in[4];
    const float* Wp  = (const float*)d_in[5];
    const float* bp  = (const float*)d_in[6];
    float* out = (float*)d_out;

    // fixed region: feat | el | er | cursor  (159.0 MB, 16B-aligned ends)
    float* ws_f   = (float*)d_ws;
    float* feat   = ws_f;                           // M*N*256
    float* el     = feat + (size_t)GM * GN * HF;    // MN*4
    float* er     = el + (size_t)MN * GH;           // MN*4
    int*   cursor = (int*)(er + (size_t)MN * GH);   // MN
    int*   after  = cursor + MN;
    size_t fixedBytes = (size_t)((char*)after - (char*)d_ws);

    // tiers: bucket{64,48}+wbuf -> compact+wbuf -> compact in-agg weights
    int cap = 0;
    if (ws_size >= fixedBytes + (size_t)MN * 64 * 20) cap = 64;
    else if (ws_size >= fixedBytes + (size_t)MN * 48 * 20) cap = 48;

    k_gemm<<<dim3((GN + 63) / 64, GH, GM), 256, 0, stream>>>(h, Wfc, al, ar, feat, el, er);

    dim3 aggGrid(GN / 4, GM);
    if (cap > 0) {
        int*    perm = after;                                  // MN*cap ints
        float4* wbuf = (float4*)(perm + (size_t)MN * cap);     // MN*cap float4
        hipMemsetAsync(cursor, 0, (size_t)MN * 4, stream);
        k_place_bucket_w<<<dim3(GE / 256, GM), 256, 0, stream>>>(ei, el, er, cursor, perm, wbuf, cap);
        k_agg<true><<<aggGrid, 256, 0, stream>>>(feat, el, er, cursor, cursor, perm, wbuf, Wp, bp, out, cap);
    } else {
        int* deg     = after;                        // MN
        int* basearr = deg + MN;                     // MN+1 (+pad to 16)
        int* perm    = basearr + MN + 16;            // M*E
        float4* wbuf = (float4*)(perm + (size_t)GM * GE);  // M*E float4 (16B-aligned)
        int useW = (ws_size >= fixedBytes + (2 * (size_t)MN + 16 + (size_t)GM * GE) * 4
                              + (size_t)GM * GE * 16) ? 1 : 0;
        hipMemsetAsync(cursor, 0, (size_t)MN * 4, stream);
        hipMemsetAsync(deg, 0, (size_t)MN * 4, stream);
        k_deg<<<dim3(GE / 256, GM), 256, 0, stream>>>(ei, deg);
        k_scan<<<1, 1024, 0, stream>>>(deg, basearr);
        k_place_w<<<dim3(GE / 256, GM), 256, 0, stream>>>(ei, el, er, basearr, cursor, perm, wbuf, useW);
        if (useW)
            k_agg<true><<<aggGrid, 256, 0, stream>>>(feat, el, er, deg, basearr, perm, wbuf, Wp, bp, out, 0);
        else
            k_agg<false><<<aggGrid, 256, 0, stream>>>(feat, el, er, deg, basearr, perm, wbuf, Wp, bp, out, 0);
    }
}

// Round 8
// 654.016 us; speedup vs baseline: 1.3881x; 1.3881x over previous
//
#include <hip/hip_runtime.h>
#include <hip/hip_bf16.h>
#include <math.h>

#define GN 50000
#define GIN 256
#define GF 64
#define GH 4
#define GM 3
#define GE 800000
#define GOUT 16
#define HF 256          // H*F
#define MN (GM*GN)      // 150000

typedef unsigned short ushort;
typedef ushort ushort8 __attribute__((ext_vector_type(8)));
typedef __bf16 bf16x8 __attribute__((ext_vector_type(8)));
typedef float f32x4 __attribute__((ext_vector_type(4)));

__device__ inline float lkexp(float x) {          // exp(leaky_relu(x))
    x = x > 0.f ? x : 0.2f * x;
    return __expf(x);                              // max-free: |logit| small, safe in f32
}
__device__ inline ushort f2bf(float f) {           // f32 -> bf16 bits (RNE)
    unsigned u = __float_as_uint(f);
    return (ushort)((u + 0x7FFFu + ((u >> 16) & 1u)) >> 16);
}

// ---------------- prep: h -> bf16 ----------------------------------------
__global__ __launch_bounds__(256) void k_prep_h(const float* __restrict__ h,
                                                ushort* __restrict__ hb) {
    const int total = GN * GIN / 8;
    for (int i = blockIdx.x * 256 + threadIdx.x; i < total; i += gridDim.x * 256) {
        float4 a = *(const float4*)&h[i * 8];
        float4 b = *(const float4*)&h[i * 8 + 4];
        ushort8 o;
        o[0]=f2bf(a.x); o[1]=f2bf(a.y); o[2]=f2bf(a.z); o[3]=f2bf(a.w);
        o[4]=f2bf(b.x); o[5]=f2bf(b.y); o[6]=f2bf(b.z); o[7]=f2bf(b.w);
        *(ushort8*)&hb[i * 8] = o;
    }
}

// ------- prep: W_fc[m][k][col] -> WbT[m][col][k] (bf16, transposed) ------
__global__ __launch_bounds__(256) void k_prep_w(const float* __restrict__ W,
                                                ushort* __restrict__ WbT) {
    int m = blockIdx.x;
    int col = threadIdx.x;                 // 256 cols
    const float* Wm = W + (size_t)m * GIN * HF;
    ushort* Tm = WbT + (size_t)m * HF * GIN;
    for (int k = 0; k < GIN; k++) {
        Tm[col * GIN + k] = f2bf(Wm[k * HF + col]);   // read coalesced across col
    }
}

// ------ MFMA GEMM: feat[m] = h @ W_fc[m] (bf16 in, f32 out) + el/er ------
// tile 128 rows x 64 cols (cols = head hh). 4 stacked waves: wave w owns
// rows w*32..w*32+31, all 64 cols -> acc[2][4] frags of 16x16, K-step 32.
__global__ __launch_bounds__(256) void k_gemm_mfma(const ushort* __restrict__ hb,
                                                   const ushort* __restrict__ WbT,
                                                   const float* __restrict__ al,
                                                   const float* __restrict__ ar,
                                                   float* __restrict__ C,
                                                   float* __restrict__ el,
                                                   float* __restrict__ er) {
    int m = blockIdx.z;
    int hh = blockIdx.y;
    int rowBase = blockIdx.x * 128;
    int colBase = hh * 64;
    const ushort* Bm = WbT + (size_t)m * HF * GIN;   // [col][k]
    float* Cm = C + (size_t)m * GN * HF;

    __shared__ ushort As[128][40];   // stride 80B (16B-mult; 20-bank spread)
    __shared__ ushort Bs[64][40];    // transposed B tile: [col][k]

    int t = threadIdx.x;
    int w = t >> 6, lane = t & 63;
    int l15 = lane & 15, lg = lane >> 4;   // fragment row/col & k-group

    f32x4 acc[2][4] = {};

    for (int k0 = 0; k0 < GIN; k0 += 32) {
        // stage A: 128 rows x 32 k; thread covers (row = idx>>2, slot = idx&3)
        #pragma unroll
        for (int l = 0; l < 2; l++) {
            int idx = t + l * 256;
            int r = idx >> 2, c8 = idx & 3;
            int row = rowBase + r;
            ushort8 v = {0,0,0,0,0,0,0,0};
            if (row < GN) v = *(const ushort8*)&hb[(size_t)row * GIN + k0 + c8 * 8];
            *(ushort8*)&As[r][c8 * 8] = v;
        }
        // stage B^T: 64 cols x 32 k
        {
            int r = t >> 2, c8 = t & 3;
            ushort8 v = *(const ushort8*)&Bm[(size_t)(colBase + r) * GIN + k0 + c8 * 8];
            *(ushort8*)&Bs[r][c8 * 8] = v;
        }
        __syncthreads();
        // frags: A row = w*32 + fr*16 + l15, k = lg*8..+7 ; B col = fc*16+l15
        bf16x8 a0 = __builtin_bit_cast(bf16x8, *(ushort8*)&As[w * 32 + l15][lg * 8]);
        bf16x8 a1 = __builtin_bit_cast(bf16x8, *(ushort8*)&As[w * 32 + 16 + l15][lg * 8]);
        #pragma unroll
        for (int fc = 0; fc < 4; fc++) {
            bf16x8 b = __builtin_bit_cast(bf16x8, *(ushort8*)&Bs[fc * 16 + l15][lg * 8]);
            acc[0][fc] = __builtin_amdgcn_mfma_f32_16x16x32_bf16(a0, b, acc[0][fc], 0, 0, 0);
            acc[1][fc] = __builtin_amdgcn_mfma_f32_16x16x32_bf16(a1, b, acc[1][fc], 0, 0, 0);
        }
        __syncthreads();
    }

    // C write: D layout col = l15, row_in_frag = lg*4 + reg  [m89-verified]
    #pragma unroll
    for (int fr = 0; fr < 2; fr++) {
        #pragma unroll
        for (int reg = 0; reg < 4; reg++) {
            int row = rowBase + w * 32 + fr * 16 + lg * 4 + reg;
            if (row < GN) {
                float* dst = &Cm[(size_t)row * HF + colBase + l15];
                dst[0]  = acc[fr][0][reg];
                dst[16] = acc[fr][1][reg];
                dst[32] = acc[fr][2][reg];
                dst[48] = acc[fr][3][reg];
            }
        }
    }
    // fused el/er: dot over this head's 64 cols; 16-lane groups hold a row
    float alv[4], arv[4];
    #pragma unroll
    for (int fc = 0; fc < 4; fc++) {
        alv[fc] = al[((size_t)m * GH + hh) * GF + fc * 16 + l15];
        arv[fc] = ar[((size_t)m * GH + hh) * GF + fc * 16 + l15];
    }
    float* elm = el + (size_t)m * GN * GH;
    float* erm = er + (size_t)m * GN * GH;
    #pragma unroll
    for (int fr = 0; fr < 2; fr++) {
        #pragma unroll
        for (int reg = 0; reg < 4; reg++) {
            float pl = acc[fr][0][reg] * alv[0] + acc[fr][1][reg] * alv[1]
                     + acc[fr][2][reg] * alv[2] + acc[fr][3][reg] * alv[3];
            float pr = acc[fr][0][reg] * arv[0] + acc[fr][1][reg] * arv[1]
                     + acc[fr][2][reg] * arv[2] + acc[fr][3][reg] * arv[3];
            #pragma unroll
            for (int o = 1; o < 16; o <<= 1) {
                pl += __shfl_xor(pl, o, 16);
                pr += __shfl_xor(pr, o, 16);
            }
            int row = rowBase + w * 32 + fr * 16 + lg * 4 + reg;
            if (l15 == 0 && row < GN) {
                elm[(size_t)row * GH + hh] = pl;
                erm[(size_t)row * GH + hh] = pr;
            }
        }
    }
}

// --------- bucket placement: 1 atomic/edge, src stored in slot -----------
__global__ __launch_bounds__(256) void k_place_bucket(const int* __restrict__ ei,
                                                      int* __restrict__ cursor,
                                                      int* __restrict__ perm,
                                                      int cap) {
    int e = blockIdx.x * 256 + threadIdx.x;
    int m = blockIdx.y;
    int src = ei[((size_t)m * 2 + 0) * GE + e];
    int dst = ei[((size_t)m * 2 + 1) * GE + e];
    int nb = m * GN + dst;
    int c = atomicAdd(&cursor[nb], 1);
    if (c < cap) perm[nb * cap + c] = src;   // clamp guard (P(deg>cap) ~ 0)
}

// ---------------- compact-CSR fallback path ------------------------------
__global__ __launch_bounds__(256) void k_deg(const int* __restrict__ ei,
                                             int* __restrict__ deg) {
    int e = blockIdx.x * 256 + threadIdx.x;
    int m = blockIdx.y;
    int dst = ei[((size_t)m * 2 + 1) * GE + e];
    atomicAdd(&deg[m * GN + dst], 1);
}

__global__ __launch_bounds__(1024) void k_scan(const int* __restrict__ deg,
                                               int* __restrict__ basearr) {
    __shared__ int s_wsum[16];
    int tid = threadIdx.x;
    int wave = tid >> 6, lane = tid & 63;
    if (tid == 0) basearr[0] = 0;
    int carry = 0;
    for (int c0 = 0; c0 < MN; c0 += 4096) {
        int idx = c0 + tid * 4;
        int v0 = (idx + 0 < MN) ? deg[idx + 0] : 0;
        int v1 = (idx + 1 < MN) ? deg[idx + 1] : 0;
        int v2 = (idx + 2 < MN) ? deg[idx + 2] : 0;
        int v3 = (idx + 3 < MN) ? deg[idx + 3] : 0;
        int s = v0 + v1 + v2 + v3;
        int sc = s;
        #pragma unroll
        for (int o = 1; o < 64; o <<= 1) {
            int u = __shfl_up(sc, o, 64);
            if (lane >= o) sc += u;
        }
        if (lane == 63) s_wsum[wave] = sc;
        __syncthreads();
        if (tid < 16) {
            int ww = s_wsum[tid];
            #pragma unroll
            for (int o = 1; o < 16; o <<= 1) {
                int u = __shfl_up(ww, o, 16);
                if (tid >= o) ww += u;
            }
            s_wsum[tid] = ww;
        }
        __syncthreads();
        int wpre = (wave == 0) ? 0 : s_wsum[wave - 1];
        int total = s_wsum[15];
        int p = carry + wpre + (sc - s);
        p += v0; if (idx + 0 < MN) basearr[idx + 1] = p;
        p += v1; if (idx + 1 < MN) basearr[idx + 2] = p;
        p += v2; if (idx + 2 < MN) basearr[idx + 3] = p;
        p += v3; if (idx + 3 < MN) basearr[idx + 4] = p;
        carry += total;
        __syncthreads();
    }
}

__global__ __launch_bounds__(256) void k_place(const int* __restrict__ ei,
                                               const int* __restrict__ basearr,
                                               int* __restrict__ cursor,
                                               int* __restrict__ perm) {
    int e = blockIdx.x * 256 + threadIdx.x;
    int m = blockIdx.y;
    int src = ei[((size_t)m * 2 + 0) * GE + e];
    int dst = ei[((size_t)m * 2 + 1) * GE + e];
    int pos = basearr[m * GN + dst] + atomicAdd(&cursor[m * GN + dst], 1);
    perm[pos] = src;
}

// ---- aggregation: wave-per-node, zero barriers, in-kernel weights -------
__global__ __launch_bounds__(256) void k_agg(const float* __restrict__ feat,
                                             const float* __restrict__ el,
                                             const float* __restrict__ er,
                                             const int* __restrict__ degArr,
                                             const int* __restrict__ basearr,
                                             const int* __restrict__ perm,
                                             const float* __restrict__ Wp,
                                             const float* __restrict__ bp,
                                             float* __restrict__ out,
                                             int cap) {
    int t = threadIdx.x;
    int w = t >> 6, lane = t & 63;
    int n = blockIdx.x * 4 + w;           // GN % 4 == 0
    int m = blockIdx.y;
    int nb = m * GN + n;
    int start, deg;
    if (cap > 0) { start = nb * cap; deg = min(degArr[nb], cap); }
    else { start = basearr[nb]; deg = basearr[nb + 1] - start; }

    __shared__ float4 s_w4[4][64];        // [wave][edge] exp weights
    __shared__ int    s_off[4][64];       // [wave][edge] feat byte offset
    __shared__ float  s_z[4][256];
    __shared__ float  s_pr[4][4][16];

    const char* featb = (const char*)(feat + (size_t)m * GN * HF);
    const float* elm = el + (size_t)m * GN * GH;
    int hl = lane >> 4;                   // head of this lane's 4 dims
    int myoff = lane * 16;
    float4 er4 = *(const float4*)&er[(size_t)nb * GH];

    float4 acc  = make_float4(0.f, 0.f, 0.f, 0.f);
    float4 dsum = make_float4(0.f, 0.f, 0.f, 0.f);

    for (int done = 0; done < deg; done += 64) {
        int cnt = min(64, deg - done);
        float4 w4 = make_float4(0.f, 0.f, 0.f, 0.f);
        if (lane < cnt) {
            int src = perm[start + done + lane];
            s_off[w][lane] = src << 10;   // HF*4 bytes per row
            float4 e4 = *(const float4*)&elm[(size_t)src * GH];
            w4 = make_float4(lkexp(e4.x + er4.x), lkexp(e4.y + er4.y),
                             lkexp(e4.z + er4.z), lkexp(e4.w + er4.w));
            s_w4[w][lane] = w4;
        }
        dsum.x += w4.x; dsum.y += w4.y; dsum.z += w4.z; dsum.w += w4.w;
        // gather (intra-wave LDS RAW ordered; no barriers anywhere)
        #pragma unroll 8
        for (int i = 0; i < cnt; i++) {
            float wgt = ((const float*)&s_w4[w][i])[hl];   // bcast per 16-group
            float4 f = *(const float4*)(featb + s_off[w][i] + myoff);
            acc.x = fmaf(wgt, f.x, acc.x);
            acc.y = fmaf(wgt, f.y, acc.y);
            acc.z = fmaf(wgt, f.z, acc.z);
            acc.w = fmaf(wgt, f.w, acc.w);
        }
    }
    #pragma unroll
    for (int o = 32; o > 0; o >>= 1) {
        dsum.x += __shfl_xor(dsum.x, o, 64);
        dsum.y += __shfl_xor(dsum.y, o, 64);
        dsum.z += __shfl_xor(dsum.z, o, 64);
        dsum.w += __shfl_xor(dsum.w, o, 64);
    }
    float dr = (hl & 1) ? ((hl & 2) ? dsum.w : dsum.y)
                        : ((hl & 2) ? dsum.z : dsum.x);
    float inv = (deg > 0) ? 1.f / dr : 0.f;
    float4 z;
    float rx = acc.x * inv; z.x = rx > 0.f ? rx : expm1f(rx);
    float ry = acc.y * inv; z.y = ry > 0.f ? ry : expm1f(ry);
    float rz = acc.z * inv; z.z = rz > 0.f ? rz : expm1f(rz);
    float rw = acc.w * inv; z.w = rw > 0.f ? rw : expm1f(rw);
    *(float4*)&s_z[w][lane * 4] = z;

    int ck = lane >> 4, o = lane & 15;
    float p = 0.f;
    #pragma unroll
    for (int v = 0; v < 64; v++) {
        int dim = ck * 64 + ((v + 8 * ck) & 63);
        p = fmaf(s_z[w][dim], Wp[dim * GOUT + o], p);
    }
    s_pr[w][ck][o] = p;
    if (lane < 16) {
        float s = bp[lane] + s_pr[w][0][lane] + s_pr[w][1][lane]
                + s_pr[w][2][lane] + s_pr[w][3][lane];
        out[(size_t)n * (GM * GOUT) + m * GOUT + lane] = s;
    }
}

extern "C" void kernel_launch(void* const* d_in, const int* in_sizes, int n_in,
                              void* d_out, int out_size, void* d_ws, size_t ws_size,
                              hipStream_t stream) {
    const float* h   = (const float*)d_in[0];
    const int*   ei  = (const int*)d_in[1];
    const float* Wfc = (const float*)d_in[2];
    const float* al  = (const float*)d_in[3];
    const float* ar  = (const float*)d_in[4];
    const float* Wp  = (const float*)d_in[5];
    const float* bp  = (const float*)d_in[6];
    float* out = (float*)d_out;

    // fixed region: feat | el | er | cursor | hb | WbT   (~185 MB)
    float*  ws_f   = (float*)d_ws;
    float*  feat   = ws_f;                           // M*N*256 f32
    float*  el     = feat + (size_t)GM * GN * HF;    // MN*4
    float*  er     = el + (size_t)MN * GH;           // MN*4
    int*    cursor = (int*)(er + (size_t)MN * GH);   // MN
    ushort* hb     = (ushort*)(cursor + MN);         // N*IN bf16
    ushort* WbT    = hb + (size_t)GN * GIN;          // M*HF*IN bf16 (transposed)
    int*    after  = (int*)(WbT + (size_t)GM * HF * GIN);
    size_t fixedBytes = (size_t)((char*)after - (char*)d_ws);

    int cap = 0;
    if (ws_size >= fixedBytes + (size_t)MN * 64 * 4) cap = 64;
    else if (ws_size >= fixedBytes + (size_t)MN * 48 * 4) cap = 48;

    k_prep_h<<<2048, 256, 0, stream>>>(h, hb);
    k_prep_w<<<GM, 256, 0, stream>>>(Wfc, WbT);
    k_gemm_mfma<<<dim3((GN + 127) / 128, GH, GM), 256, 0, stream>>>(hb, WbT, al, ar, feat, el, er);

    dim3 aggGrid(GN / 4, GM);
    if (cap > 0) {
        int* perm = after;                           // MN*cap
        hipMemsetAsync(cursor, 0, (size_t)MN * 4, stream);
        k_place_bucket<<<dim3(GE / 256, GM), 256, 0, stream>>>(ei, cursor, perm, cap);
        k_agg<<<aggGrid, 256, 0, stream>>>(feat, el, er, cursor, cursor, perm, Wp, bp, out, cap);
    } else {
        int* deg     = after;                        // MN
        int* basearr = deg + MN;                     // MN+1 (+pad)
        int* perm    = basearr + MN + 16;            // M*E
        hipMemsetAsync(cursor, 0, (size_t)MN * 4, stream);
        hipMemsetAsync(deg, 0, (size_t)MN * 4, stream);
        k_deg<<<dim3(GE / 256, GM), 256, 0, stream>>>(ei, deg);
        k_scan<<<1, 1024, 0, stream>>>(deg, basearr);
        k_place<<<dim3(GE / 256, GM), 256, 0, stream>>>(ei, basearr, cursor, perm);
        k_agg<<<aggGrid, 256, 0, stream>>>(feat, el, er, deg, basearr, perm, Wp, bp, out, 0);
    }
}

// Round 9
// 653.710 us; speedup vs baseline: 1.3888x; 1.0005x over previous
//
#include <hip/hip_runtime.h>
#include <hip/hip_bf16.h>
#include <math.h>

#define GN 50000
#define GIN 256
#define GF 64
#define GH 4
#define GM 3
#define GE 800000
#define GOUT 16
#define HF 256          // H*F
#define MN (GM*GN)      // 150000

typedef unsigned short ushort;
typedef ushort ushort8 __attribute__((ext_vector_type(8)));
typedef __bf16 bf16x8 __attribute__((ext_vector_type(8)));
typedef float f32x4 __attribute__((ext_vector_type(4)));

__device__ inline float lkexp(float x) {          // exp(leaky_relu(x))
    x = x > 0.f ? x : 0.2f * x;
    return __expf(x);                              // max-free: |logit| small, safe in f32
}
__device__ inline ushort f2bf(float f) {           // f32 -> bf16 bits (RNE)
    unsigned u = __float_as_uint(f);
    return (ushort)((u + 0x7FFFu + ((u >> 16) & 1u)) >> 16);
}
__device__ inline float bf2f(ushort u) {
    return __uint_as_float(((unsigned)u) << 16);
}

// ---------------- prep: h -> bf16 ----------------------------------------
__global__ __launch_bounds__(256) void k_prep_h(const float* __restrict__ h,
                                                ushort* __restrict__ hb) {
    const int total = GN * GIN / 8;
    for (int i = blockIdx.x * 256 + threadIdx.x; i < total; i += gridDim.x * 256) {
        float4 a = *(const float4*)&h[i * 8];
        float4 b = *(const float4*)&h[i * 8 + 4];
        ushort8 o;
        o[0]=f2bf(a.x); o[1]=f2bf(a.y); o[2]=f2bf(a.z); o[3]=f2bf(a.w);
        o[4]=f2bf(b.x); o[5]=f2bf(b.y); o[6]=f2bf(b.z); o[7]=f2bf(b.w);
        *(ushort8*)&hb[i * 8] = o;
    }
}

// ------- prep: W_fc[m][k][col] -> WbT[m][col][k] (bf16, LDS-tiled) -------
__global__ __launch_bounds__(256) void k_prep_w(const float* __restrict__ W,
                                                ushort* __restrict__ WbT) {
    int m = blockIdx.z;
    int k0 = blockIdx.x * 32, c0 = blockIdx.y * 32;
    __shared__ float tile[32][33];
    int tx = threadIdx.x & 31, ty = threadIdx.x >> 5;   // ty 0..7
    const float* Wm = W + (size_t)m * GIN * HF;
    ushort* Tm = WbT + (size_t)m * HF * GIN;
    #pragma unroll
    for (int r = 0; r < 4; r++)
        tile[ty + 8 * r][tx] = Wm[(size_t)(k0 + ty + 8 * r) * HF + c0 + tx];
    __syncthreads();
    #pragma unroll
    for (int r = 0; r < 4; r++)
        Tm[(size_t)(c0 + ty + 8 * r) * GIN + k0 + tx] = f2bf(tile[tx][ty + 8 * r]);
}

// ------------- prep: W_pred[dim][o] -> WpT[o][dim] (f32) -----------------
__global__ __launch_bounds__(256) void k_prep_wp(const float* __restrict__ Wp,
                                                 float* __restrict__ WpT) {
    int t = threadIdx.x;
    #pragma unroll
    for (int o = 0; o < GOUT; o++) WpT[o * HF + t] = Wp[t * GOUT + o];
}

// ------ MFMA GEMM: feat[m] = h @ W_fc[m] (bf16 in, bf16 out) + el/er -----
// tile 128 rows x 64 cols (cols = head hh). wave w owns rows w*32..+31.
__global__ __launch_bounds__(256) void k_gemm_mfma(const ushort* __restrict__ hb,
                                                   const ushort* __restrict__ WbT,
                                                   const float* __restrict__ al,
                                                   const float* __restrict__ ar,
                                                   ushort* __restrict__ C,
                                                   float* __restrict__ el,
                                                   float* __restrict__ er) {
    int m = blockIdx.z;
    int hh = blockIdx.y;
    int rowBase = blockIdx.x * 128;
    int colBase = hh * 64;
    const ushort* Bm = WbT + (size_t)m * HF * GIN;   // [col][k]
    ushort* Cm = C + (size_t)m * GN * HF;

    __shared__ ushort As[128][40];   // stride 80B (16B-mult)
    __shared__ ushort Bs[64][40];    // transposed B tile: [col][k]

    int t = threadIdx.x;
    int w = t >> 6, lane = t & 63;
    int l15 = lane & 15, lg = lane >> 4;

    f32x4 acc[2][4] = {};

    for (int k0 = 0; k0 < GIN; k0 += 32) {
        #pragma unroll
        for (int l = 0; l < 2; l++) {
            int idx = t + l * 256;
            int r = idx >> 2, c8 = idx & 3;
            int row = rowBase + r;
            ushort8 v = {0,0,0,0,0,0,0,0};
            if (row < GN) v = *(const ushort8*)&hb[(size_t)row * GIN + k0 + c8 * 8];
            *(ushort8*)&As[r][c8 * 8] = v;
        }
        {
            int r = t >> 2, c8 = t & 3;
            ushort8 v = *(const ushort8*)&Bm[(size_t)(colBase + r) * GIN + k0 + c8 * 8];
            *(ushort8*)&Bs[r][c8 * 8] = v;
        }
        __syncthreads();
        bf16x8 a0 = __builtin_bit_cast(bf16x8, *(ushort8*)&As[w * 32 + l15][lg * 8]);
        bf16x8 a1 = __builtin_bit_cast(bf16x8, *(ushort8*)&As[w * 32 + 16 + l15][lg * 8]);
        #pragma unroll
        for (int fc = 0; fc < 4; fc++) {
            bf16x8 b = __builtin_bit_cast(bf16x8, *(ushort8*)&Bs[fc * 16 + l15][lg * 8]);
            acc[0][fc] = __builtin_amdgcn_mfma_f32_16x16x32_bf16(a0, b, acc[0][fc], 0, 0, 0);
            acc[1][fc] = __builtin_amdgcn_mfma_f32_16x16x32_bf16(a1, b, acc[1][fc], 0, 0, 0);
        }
        __syncthreads();
    }

    // C write (bf16): D layout col = l15, row_in_frag = lg*4 + reg
    #pragma unroll
    for (int fr = 0; fr < 2; fr++) {
        #pragma unroll
        for (int reg = 0; reg < 4; reg++) {
            int row = rowBase + w * 32 + fr * 16 + lg * 4 + reg;
            if (row < GN) {
                ushort* dst = &Cm[(size_t)row * HF + colBase + l15];
                dst[0]  = f2bf(acc[fr][0][reg]);
                dst[16] = f2bf(acc[fr][1][reg]);
                dst[32] = f2bf(acc[fr][2][reg]);
                dst[48] = f2bf(acc[fr][3][reg]);
            }
        }
    }
    // fused el/er from f32 acc (full precision attention logits)
    float alv[4], arv[4];
    #pragma unroll
    for (int fc = 0; fc < 4; fc++) {
        alv[fc] = al[((size_t)m * GH + hh) * GF + fc * 16 + l15];
        arv[fc] = ar[((size_t)m * GH + hh) * GF + fc * 16 + l15];
    }
    float* elm = el + (size_t)m * GN * GH;
    float* erm = er + (size_t)m * GN * GH;
    #pragma unroll
    for (int fr = 0; fr < 2; fr++) {
        #pragma unroll
        for (int reg = 0; reg < 4; reg++) {
            float pl = acc[fr][0][reg] * alv[0] + acc[fr][1][reg] * alv[1]
                     + acc[fr][2][reg] * alv[2] + acc[fr][3][reg] * alv[3];
            float pr = acc[fr][0][reg] * arv[0] + acc[fr][1][reg] * arv[1]
                     + acc[fr][2][reg] * arv[2] + acc[fr][3][reg] * arv[3];
            #pragma unroll
            for (int o = 1; o < 16; o <<= 1) {
                pl += __shfl_xor(pl, o, 16);
                pr += __shfl_xor(pr, o, 16);
            }
            int row = rowBase + w * 32 + fr * 16 + lg * 4 + reg;
            if (l15 == 0 && row < GN) {
                elm[(size_t)row * GH + hh] = pl;
                erm[(size_t)row * GH + hh] = pr;
            }
        }
    }
}

// --------- bucket placement: 1 atomic/edge, src stored in slot -----------
__global__ __launch_bounds__(256) void k_place_bucket(const int* __restrict__ ei,
                                                      int* __restrict__ cursor,
                                                      int* __restrict__ perm,
                                                      int cap) {
    int e = blockIdx.x * 256 + threadIdx.x;
    int m = blockIdx.y;
    int src = ei[((size_t)m * 2 + 0) * GE + e];
    int dst = ei[((size_t)m * 2 + 1) * GE + e];
    int nb = m * GN + dst;
    int c = atomicAdd(&cursor[nb], 1);
    if (c < cap) perm[nb * cap + c] = src;   // clamp guard (P(deg>cap) ~ 0)
}

// ---------------- compact-CSR fallback path ------------------------------
__global__ __launch_bounds__(256) void k_deg(const int* __restrict__ ei,
                                             int* __restrict__ deg) {
    int e = blockIdx.x * 256 + threadIdx.x;
    int m = blockIdx.y;
    int dst = ei[((size_t)m * 2 + 1) * GE + e];
    atomicAdd(&deg[m * GN + dst], 1);
}

__global__ __launch_bounds__(1024) void k_scan(const int* __restrict__ deg,
                                               int* __restrict__ basearr) {
    __shared__ int s_wsum[16];
    int tid = threadIdx.x;
    int wave = tid >> 6, lane = tid & 63;
    if (tid == 0) basearr[0] = 0;
    int carry = 0;
    for (int c0 = 0; c0 < MN; c0 += 4096) {
        int idx = c0 + tid * 4;
        int v0 = (idx + 0 < MN) ? deg[idx + 0] : 0;
        int v1 = (idx + 1 < MN) ? deg[idx + 1] : 0;
        int v2 = (idx + 2 < MN) ? deg[idx + 2] : 0;
        int v3 = (idx + 3 < MN) ? deg[idx + 3] : 0;
        int s = v0 + v1 + v2 + v3;
        int sc = s;
        #pragma unroll
        for (int o = 1; o < 64; o <<= 1) {
            int u = __shfl_up(sc, o, 64);
            if (lane >= o) sc += u;
        }
        if (lane == 63) s_wsum[wave] = sc;
        __syncthreads();
        if (tid < 16) {
            int ww = s_wsum[tid];
            #pragma unroll
            for (int o = 1; o < 16; o <<= 1) {
                int u = __shfl_up(ww, o, 16);
                if (tid >= o) ww += u;
            }
            s_wsum[tid] = ww;
        }
        __syncthreads();
        int wpre = (wave == 0) ? 0 : s_wsum[wave - 1];
        int total = s_wsum[15];
        int p = carry + wpre + (sc - s);
        p += v0; if (idx + 0 < MN) basearr[idx + 1] = p;
        p += v1; if (idx + 1 < MN) basearr[idx + 2] = p;
        p += v2; if (idx + 2 < MN) basearr[idx + 3] = p;
        p += v3; if (idx + 3 < MN) basearr[idx + 4] = p;
        carry += total;
        __syncthreads();
    }
}

__global__ __launch_bounds__(256) void k_place(const int* __restrict__ ei,
                                               const int* __restrict__ basearr,
                                               int* __restrict__ cursor,
                                               int* __restrict__ perm) {
    int e = blockIdx.x * 256 + threadIdx.x;
    int m = blockIdx.y;
    int src = ei[((size_t)m * 2 + 0) * GE + e];
    int dst = ei[((size_t)m * 2 + 1) * GE + e];
    int pos = basearr[m * GN + dst] + atomicAdd(&cursor[m * GN + dst], 1);
    perm[pos] = src;
}

// ---- aggregation: wave-per-node, bf16 feat (2 rows/iter), no barriers ---
__global__ __launch_bounds__(256) void k_agg(const ushort* __restrict__ feat,
                                             const float* __restrict__ el,
                                             const float* __restrict__ er,
                                             const int* __restrict__ degArr,
                                             const int* __restrict__ basearr,
                                             const int* __restrict__ perm,
                                             const float* __restrict__ WpT,
                                             const float* __restrict__ bp,
                                             float* __restrict__ out,
                                             int cap) {
    int t = threadIdx.x;
    int w = t >> 6, lane = t & 63;
    int n = blockIdx.x * 4 + w;           // GN % 4 == 0
    int m = blockIdx.y;
    int nb = m * GN + n;
    int start, deg;
    if (cap > 0) { start = nb * cap; deg = min(degArr[nb], cap); }
    else { start = basearr[nb]; deg = basearr[nb + 1] - start; }

    __shared__ float4 s_w4[4][64];        // [wave][edge] exp weights (4 heads)
    __shared__ int    s_off[4][64];       // [wave][edge] feat byte offset
    __shared__ float  s_z[4][256];
    __shared__ float  s_pr[4][4][16];

    const char* featb = (const char*)(feat + (size_t)m * GN * HF);
    const float* elm = el + (size_t)m * GN * GH;
    float4 er4 = *(const float4*)&er[(size_t)nb * GH];

    int half = lane >> 5;                 // row parity this lane handles
    int q = lane & 31;                    // dim-group: dims q*8..q*8+7
    int qoff = q << 4;                    // byte offset within 512B row
    int hq = q >> 3;                      // head of this lane's dims

    float a0=0.f,a1=0.f,a2=0.f,a3=0.f,a4=0.f,a5=0.f,a6=0.f,a7=0.f;
    float4 dsum = make_float4(0.f, 0.f, 0.f, 0.f);

    for (int done = 0; done < deg; done += 64) {
        int cnt = min(64, deg - done);
        float4 w4 = make_float4(0.f, 0.f, 0.f, 0.f);
        int offv = 0;
        if (lane < cnt) {
            int src = perm[start + done + lane];
            offv = src << 9;              // 512B per bf16 row
            float4 e4 = *(const float4*)&elm[(size_t)src * GH];
            w4 = make_float4(lkexp(e4.x + er4.x), lkexp(e4.y + er4.y),
                             lkexp(e4.z + er4.z), lkexp(e4.w + er4.w));
        }
        s_off[w][lane] = offv;            // pad slots: 0 (row 0, weight 0)
        s_w4[w][lane] = w4;
        dsum.x += w4.x; dsum.y += w4.y; dsum.z += w4.z; dsum.w += w4.w;
        // gather: 2 rows per iteration (half 0/1); intra-wave LDS RAW ordered
        #pragma unroll 4
        for (int i = 0; i < cnt; i += 2) {
            int r = i + half;             // r==cnt (odd tail) hits zeroed slot
            float wgt = ((const float*)&s_w4[w][r])[hq];
            ushort8 v = *(const ushort8*)(featb + s_off[w][r] + qoff);
            a0 = fmaf(wgt, bf2f(v[0]), a0);
            a1 = fmaf(wgt, bf2f(v[1]), a1);
            a2 = fmaf(wgt, bf2f(v[2]), a2);
            a3 = fmaf(wgt, bf2f(v[3]), a3);
            a4 = fmaf(wgt, bf2f(v[4]), a4);
            a5 = fmaf(wgt, bf2f(v[5]), a5);
            a6 = fmaf(wgt, bf2f(v[6]), a6);
            a7 = fmaf(wgt, bf2f(v[7]), a7);
        }
    }
    // combine the two row-halves
    a0 += __shfl_xor(a0, 32, 64); a1 += __shfl_xor(a1, 32, 64);
    a2 += __shfl_xor(a2, 32, 64); a3 += __shfl_xor(a3, 32, 64);
    a4 += __shfl_xor(a4, 32, 64); a5 += __shfl_xor(a5, 32, 64);
    a6 += __shfl_xor(a6, 32, 64); a7 += __shfl_xor(a7, 32, 64);
    // denominators
    #pragma unroll
    for (int o = 32; o > 0; o >>= 1) {
        dsum.x += __shfl_xor(dsum.x, o, 64);
        dsum.y += __shfl_xor(dsum.y, o, 64);
        dsum.z += __shfl_xor(dsum.z, o, 64);
        dsum.w += __shfl_xor(dsum.w, o, 64);
    }
    float dr = (hq & 1) ? ((hq & 2) ? dsum.w : dsum.y)
                        : ((hq & 2) ? dsum.z : dsum.x);
    float inv = (deg > 0) ? 1.f / dr : 0.f;
    if (lane < 32) {
        float4 z0, z1;
        float r0=a0*inv; z0.x = r0>0.f ? r0 : expm1f(r0);
        float r1=a1*inv; z0.y = r1>0.f ? r1 : expm1f(r1);
        float r2=a2*inv; z0.z = r2>0.f ? r2 : expm1f(r2);
        float r3=a3*inv; z0.w = r3>0.f ? r3 : expm1f(r3);
        float r4=a4*inv; z1.x = r4>0.f ? r4 : expm1f(r4);
        float r5=a5*inv; z1.y = r5>0.f ? r5 : expm1f(r5);
        float r6=a6*inv; z1.z = r6>0.f ? r6 : expm1f(r6);
        float r7=a7*inv; z1.w = r7>0.f ? r7 : expm1f(r7);
        *(float4*)&s_z[w][q * 8]     = z0;
        *(float4*)&s_z[w][q * 8 + 4] = z1;
    }
    // pred head: lane (ck,o); z via b128, WpT via dwordx4; ck-rotated dims
    int ck = lane >> 4, o = lane & 15;
    const float* wpt = WpT + o * HF;
    float p = 0.f;
    #pragma unroll
    for (int v = 0; v < 16; v++) {
        int dim = ck * 64 + (((v + ck * 4) & 15) << 2);
        float4 z4 = *(const float4*)&s_z[w][dim];
        float4 wv = *(const float4*)&wpt[dim];
        p += z4.x * wv.x + z4.y * wv.y + z4.z * wv.z + z4.w * wv.w;
    }
    s_pr[w][ck][o] = p;
    if (lane < 16) {
        float s = bp[lane] + s_pr[w][0][lane] + s_pr[w][1][lane]
                + s_pr[w][2][lane] + s_pr[w][3][lane];
        out[(size_t)n * (GM * GOUT) + m * GOUT + lane] = s;
    }
}

extern "C" void kernel_launch(void* const* d_in, const int* in_sizes, int n_in,
                              void* d_out, int out_size, void* d_ws, size_t ws_size,
                              hipStream_t stream) {
    const float* h   = (const float*)d_in[0];
    const int*   ei  = (const int*)d_in[1];
    const float* Wfc = (const float*)d_in[2];
    const float* al  = (const float*)d_in[3];
    const float* ar  = (const float*)d_in[4];
    const float* Wp  = (const float*)d_in[5];
    const float* bp  = (const float*)d_in[6];
    float* out = (float*)d_out;

    // fixed region: featB(bf16) | el | er | cursor | hb | WbT | WpT  (~110 MB)
    ushort* featB  = (ushort*)d_ws;                      // M*N*256 bf16
    float*  el     = (float*)(featB + (size_t)GM * GN * HF);
    float*  er     = el + (size_t)MN * GH;
    int*    cursor = (int*)(er + (size_t)MN * GH);       // MN
    ushort* hb     = (ushort*)(cursor + MN);             // N*IN bf16
    ushort* WbT    = hb + (size_t)GN * GIN;              // M*HF*IN bf16
    float*  WpT    = (float*)(WbT + (size_t)GM * HF * GIN);  // 16*256 f32
    int*    after  = (int*)(WpT + GOUT * HF);
    size_t fixedBytes = (size_t)((char*)after - (char*)d_ws);

    int cap = 0;
    if (ws_size >= fixedBytes + (size_t)MN * 64 * 4) cap = 64;
    else if (ws_size >= fixedBytes + (size_t)MN * 48 * 4) cap = 48;

    k_prep_h<<<2048, 256, 0, stream>>>(h, hb);
    k_prep_w<<<dim3(8, 8, GM), 256, 0, stream>>>(Wfc, WbT);
    k_prep_wp<<<1, 256, 0, stream>>>(Wp, WpT);
    k_gemm_mfma<<<dim3((GN + 127) / 128, GH, GM), 256, 0, stream>>>(hb, WbT, al, ar, featB, el, er);

    dim3 aggGrid(GN / 4, GM);
    if (cap > 0) {
        int* perm = after;                           // MN*cap
        hipMemsetAsync(cursor, 0, (size_t)MN * 4, stream);
        k_place_bucket<<<dim3(GE / 256, GM), 256, 0, stream>>>(ei, cursor, perm, cap);
        k_agg<<<aggGrid, 256, 0, stream>>>(featB, el, er, cursor, cursor, perm, WpT, bp, out, cap);
    } else {
        int* deg     = after;                        // MN
        int* basearr = deg + MN;                     // MN+1 (+pad)
        int* perm    = basearr + MN + 16;            // M*E
        hipMemsetAsync(cursor, 0, (size_t)MN * 4, stream);
        hipMemsetAsync(deg, 0, (size_t)MN * 4, stream);
        k_deg<<<dim3(GE / 256, GM), 256, 0, stream>>>(ei, deg);
        k_scan<<<1, 1024, 0, stream>>>(deg, basearr);
        k_place<<<dim3(GE / 256, GM), 256, 0, stream>>>(ei, basearr, cursor, perm);
        k_agg<<<aggGrid, 256, 0, stream>>>(featB, el, er, deg, basearr, perm, WpT, bp, out, 0);
    }
}